// Round 3
// baseline (248.379 us; speedup 1.0000x reference)
//
#include <hip/hip_runtime.h>
#include <hip/hip_bf16.h>

#define BB 4
#define SS 2048
#define EE 512
#define HH 8
#define DD 64

typedef __attribute__((ext_vector_type(8))) short bf16x8;   // 8 bf16 = 4 VGPRs
typedef __attribute__((ext_vector_type(4))) float f32x4;
typedef __attribute__((ext_vector_type(4))) unsigned int u32x4;

__device__ __forceinline__ unsigned short f2bf(float f) {
    __hip_bfloat16 h = __float2bfloat16(f);   // round-to-nearest
    return *reinterpret_cast<unsigned short*>(&h);
}

// HW packed f32->bf16 (RTNE). lo -> low 16, hi -> high 16 (T12 recipe).
__device__ __forceinline__ unsigned int cvtpk(float lo, float hi) {
    unsigned int r;
    asm("v_cvt_pk_bf16_f32 %0, %1, %2" : "=v"(r) : "v"(lo), "v"(hi));
    return r;
}

// gfx950 half-wave swaps (T12).
__device__ __forceinline__ void pl32(unsigned int& a, unsigned int& b) {
    asm("v_permlane32_swap_b32 %0, %1" : "+v"(a), "+v"(b));
}
__device__ __forceinline__ void pl16(unsigned int& a, unsigned int& b) {
    asm("v_permlane16_swap_b32 %0, %1" : "+v"(a), "+v"(b));
}

// Async global->LDS DMA, 16 B per lane (GEMM staging only).
__device__ __forceinline__ void gll16(const unsigned short* g, unsigned short* l) {
    __builtin_amdgcn_global_load_lds(
        (const __attribute__((address_space(1))) unsigned int*)g,
        (__attribute__((address_space(3))) unsigned int*)l,
        16, 0, 0);
}

// ---------------------------------------------------------------------------
// fp32 -> bf16 cast, 5 tensors in one launch (blockIdx.y selects).
// ---------------------------------------------------------------------------
__global__ __launch_bounds__(256)
void cast_all(const float* __restrict__ x,
              const float* __restrict__ wq, const float* __restrict__ wk,
              const float* __restrict__ wv, const float* __restrict__ wo,
              unsigned short* __restrict__ xb,
              unsigned short* __restrict__ wqb, unsigned short* __restrict__ wkb,
              unsigned short* __restrict__ wvb, unsigned short* __restrict__ wob)
{
    const int t = blockIdx.y;
    const float* src; unsigned short* dst; int n4;
    switch (t) {
        case 0: src = x;  dst = xb;  n4 = (BB*SS*EE)/4; break;
        case 1: src = wq; dst = wqb; n4 = (EE*EE)/4; break;
        case 2: src = wk; dst = wkb; n4 = (EE*EE)/4; break;
        case 3: src = wv; dst = wvb; n4 = (EE*EE)/4; break;
        default: src = wo; dst = wob; n4 = (EE*EE)/4; break;
    }
    const int i = blockIdx.x * 256 + threadIdx.x;
    if (i >= n4) return;
    const float4 v = reinterpret_cast<const float4*>(src)[i];
    ushort4 o;
    o.x = f2bf(v.x); o.y = f2bf(v.y); o.z = f2bf(v.z); o.w = f2bf(v.w);
    reinterpret_cast<ushort4*>(dst)[i] = o;
}

// ---------------------------------------------------------------------------
// MFMA GEMM, m97-style: C = A(bf16)[M,K] @ W(bf16)[N,K]^T + bias.
// (unchanged from round 2 — passed)
// ---------------------------------------------------------------------------
template<typename OutT, bool TRANSPOSE_V, int TM>
__global__ __launch_bounds__(256)
void gemm_mfma_nt(const unsigned short* __restrict__ A,
                  const unsigned short* __restrict__ W0, const float* __restrict__ b0, OutT* __restrict__ C0,
                  const unsigned short* __restrict__ W1, const float* __restrict__ b1, OutT* __restrict__ C1,
                  const unsigned short* __restrict__ W2, const float* __restrict__ b2, OutT* __restrict__ C2,
                  const float* __restrict__ rowscale,
                  int M, int N, int K)
{
    const unsigned short* W = (blockIdx.z == 0) ? W0 : (blockIdx.z == 1) ? W1 : W2;
    const float* bias       = (blockIdx.z == 0) ? b0 : (blockIdx.z == 1) ? b1 : b2;
    OutT* C                 = (blockIdx.z == 0) ? C0 : (blockIdx.z == 1) ? C1 : C2;

    constexpr int MT = TM / 32;             // m-tiles of 16 per wave (4 or 2)
    __shared__ unsigned short As[TM * 32];  // [row][32] chunk-swizzled
    __shared__ unsigned short Bs[128 * 32];

    const int tid  = threadIdx.x;
    const int wave = tid >> 6, lane = tid & 63;
    const int quad = lane >> 4, r16 = lane & 15;
    const int m0 = blockIdx.x * TM, n0 = blockIdx.y * 128;
    const int wm0 = (wave >> 1) * (TM / 2), wn0 = (wave & 1) * 64;

    f32x4 acc[MT][4];
    const f32x4 zero = {0.f, 0.f, 0.f, 0.f};
    #pragma unroll
    for (int i = 0; i < MT; ++i)
        #pragma unroll
        for (int j = 0; j < 4; ++j) acc[i][j] = zero;

    const int swz = (r16 >> 1) & 3;   // fragment-read chunk swizzle

    for (int k0 = 0; k0 < K; k0 += 32) {
        __syncthreads();   // previous iteration's frag reads done
        #pragma unroll
        for (int j = 0; j < TM / 64; ++j) {
            const int cb = wave * 64 + j * 256;       // wave-uniform chunk base
            const int c  = cb + lane;                 // this lane's chunk
            const int row = c >> 2, cc = (c & 3) ^ ((row >> 1) & 3);
            gll16(&A[(size_t)(m0 + row) * K + k0 + cc * 8], &As[cb * 8]);
        }
        #pragma unroll
        for (int j = 0; j < 2; ++j) {
            const int cb = wave * 64 + j * 256;
            const int c  = cb + lane;
            const int row = c >> 2, cc = (c & 3) ^ ((row >> 1) & 3);
            gll16(&W[(size_t)(n0 + row) * K + k0 + cc * 8], &Bs[cb * 8]);
        }
        __syncthreads();   // vmcnt(0) drain completes the DMA
        bf16x8 af[MT], bfr[4];
        #pragma unroll
        for (int t = 0; t < MT; ++t)
            af[t]  = *reinterpret_cast<bf16x8*>(&As[((wm0 + t * 16 + r16) * 4 + (quad ^ swz)) * 8]);
        #pragma unroll
        for (int t = 0; t < 4; ++t)
            bfr[t] = *reinterpret_cast<bf16x8*>(&Bs[((wn0 + t * 16 + r16) * 4 + (quad ^ swz)) * 8]);
        #pragma unroll
        for (int mt = 0; mt < MT; ++mt)
            #pragma unroll
            for (int nt = 0; nt < 4; ++nt)
                acc[mt][nt] = __builtin_amdgcn_mfma_f32_16x16x32_bf16(
                    af[mt], bfr[nt], acc[mt][nt], 0, 0, 0);
    }

    // Epilogue. C/D layout: col = lane&15, row = quad*4 + reg (m89-verified).
    if (TRANSPOSE_V && blockIdx.z == 2) {
        #pragma unroll
        for (int mt = 0; mt < MT; ++mt) {
            const int m = m0 + wm0 + mt * 16 + quad * 4;   // 4 consecutive rows
            const int bb = m >> 11, s0 = m & (SS - 1);
            #pragma unroll
            for (int nt = 0; nt < 4; ++nt) {
                const int col = n0 + wn0 + nt * 16 + r16;
                const float bv = bias[col];
                uint2 o;
                o.x = cvtpk(acc[mt][nt][0] + bv, acc[mt][nt][1] + bv);
                o.y = cvtpk(acc[mt][nt][2] + bv, acc[mt][nt][3] + bv);
                *reinterpret_cast<uint2*>(
                    &((unsigned short*)C2)[(size_t)bb * EE * SS + (size_t)col * SS + s0]) = o;
            }
        }
        return;
    }
    const bool doscale = (rowscale != nullptr) && (blockIdx.z == 0);
    #pragma unroll
    for (int mt = 0; mt < MT; ++mt) {
        float rs[4];
        #pragma unroll
        for (int r = 0; r < 4; ++r) {
            const int row = m0 + wm0 + mt * 16 + quad * 4 + r;
            rs[r] = doscale ? rowscale[row & (SS - 1)] * 0.18033688f : 1.0f;
        }
        #pragma unroll
        for (int nt = 0; nt < 4; ++nt) {
            const int col = n0 + wn0 + nt * 16 + r16;
            const float bv = bias[col];
            #pragma unroll
            for (int r = 0; r < 4; ++r) {
                const int row = m0 + wm0 + mt * 16 + quad * 4 + r;
                const float v = (acc[mt][nt][r] + bv) * rs[r];
                if constexpr (sizeof(OutT) == 2)
                    C[(size_t)row * N + col] = (OutT)f2bf(v);
                else
                    C[(size_t)row * N + col] = (OutT)v;
            }
        }
    }
}

// ---------------------------------------------------------------------------
// MFMA flash attention, round 11: NO LDS STAGING (K/V are L2-resident —
// FETCH=12 MB; Common-mistake #7: don't stage what caches).
//  - 2x2 wave split: wave = (qh, ks) owns a 32q x 32k quadrant. Each wave
//    loads only ITS K-slice A-frags (4 KB) and V-slice B-frags (4 KB)
//    DIRECTLY from global (L2 hit). LDS read traffic in the loop: zero.
//    Barriers in the loop: zero — waves drift freely, latency-hidden by
//    8 independent loads/iter and 16 waves/CU.
//  - S^T tiles st[kt2][qt] have the same lane structure as round 2 (kt2
//    plays tn's role) -> identical pl32+pl16 P-redistribution (verified).
//  - PV unchanged: 16x16x32, o_acc[qt][dt] partial over the wave's k-slice.
//  - Epilogue: one barrier; ks=1 waves dump partial O (+l) to LDS, ks=0
//    waves add, normalize by the pair-summed l, store.
//  - __launch_bounds__(256,4) caps VGPRs at 128 so the XCD-pinned 4
//    blocks/CU stay co-resident (round-1 lesson).
// ---------------------------------------------------------------------------
__global__ __launch_bounds__(256, 4)
void attn_mfma(const unsigned short* __restrict__ Q,
               const unsigned short* __restrict__ K,
               const unsigned short* __restrict__ Vt,
               unsigned short* __restrict__ O)
{
    __shared__ float red[2][32 * 64];   // 16 KB: cross-wave O partials
    __shared__ float lred[4][32];       // 512 B: cross-wave l partials

    const int tid  = threadIdx.x;
    const int wave = tid >> 6, lane = tid & 63;
    const int quad = lane >> 4, r16 = lane & 15;
    const int qh = wave >> 1, ks = wave & 1;     // q-half, k-slice
    const int h  = blockIdx.x;                   // h on blockIdx.x -> XCD = h
    const int q0 = blockIdx.y * 64;
    const int b  = blockIdx.z;
    const size_t base    = (size_t)b * SS * EE + (size_t)h * DD;   // Q/K/O rows
    const size_t base_vt = ((size_t)b * HH + h) * DD * SS;         // Vt rows

    const int qw0 = q0 + qh * 32;

    // Q B-frags once: qf[qt][dh] = Q[q = qw0+qt*16+r16][d = dh*32+quad*8 ..]
    bf16x8 qf[2][2];
    #pragma unroll
    for (int qt = 0; qt < 2; ++qt)
        #pragma unroll
        for (int dh = 0; dh < 2; ++dh)
            qf[qt][dh] = *reinterpret_cast<const bf16x8*>(
                &Q[base + (size_t)(qw0 + qt * 16 + r16) * EE + dh * 32 + quad * 8]);

    // Per-lane global frag bases (loop adds kb offsets).
    const unsigned short* Kp = &K[base + (size_t)(ks * 32 + r16) * EE + quad * 8];
    const unsigned short* Vp = &Vt[base_vt + (size_t)r16 * SS + ks * 32 + quad * 8];

    float l_lane[2] = {0.f, 0.f};
    f32x4 o_acc[2][4];
    const f32x4 zero = {0.f, 0.f, 0.f, 0.f};
    #pragma unroll
    for (int qt = 0; qt < 2; ++qt)
        #pragma unroll
        for (int dt = 0; dt < 4; ++dt) o_acc[qt][dt] = zero;

    for (int kt = 0; kt < SS / 64; ++kt) {
        const int kb = kt * 64;

        // K A-frags first (QK^T needs them soonest), then V B-frags.
        bf16x8 kf[2][2];
        #pragma unroll
        for (int kt2 = 0; kt2 < 2; ++kt2)
            #pragma unroll
            for (int dh = 0; dh < 2; ++dh)
                kf[kt2][dh] = *reinterpret_cast<const bf16x8*>(
                    &Kp[(size_t)(kb + kt2 * 16) * EE + dh * 32]);
        bf16x8 vf[4];
        #pragma unroll
        for (int dt = 0; dt < 4; ++dt)
            vf[dt] = *reinterpret_cast<const bf16x8*>(
                &Vp[(size_t)(dt * 16) * SS + kb]);

        // S^T: st[kt2][qt]; lane holds S[q=qw0+qt*16+r16][k=ks*32+kt2*16+quad*4+r]
        f32x4 st[2][2];
        #pragma unroll
        for (int kt2 = 0; kt2 < 2; ++kt2)
            #pragma unroll
            for (int qt = 0; qt < 2; ++qt) st[kt2][qt] = zero;
        #pragma unroll
        for (int kt2 = 0; kt2 < 2; ++kt2)
            #pragma unroll
            for (int qt = 0; qt < 2; ++qt) {
                st[kt2][qt] = __builtin_amdgcn_mfma_f32_16x16x32_bf16(kf[kt2][0], qf[qt][0], st[kt2][qt], 0, 0, 0);
                st[kt2][qt] = __builtin_amdgcn_mfma_f32_16x16x32_bf16(kf[kt2][1], qf[qt][1], st[kt2][qt], 0, 0, 0);
            }

        // m=0 softmax (scale pre-folded into Q); pack to bf16 pairs in-reg.
        unsigned int wq[2][2][2];
        #pragma unroll
        for (int qt = 0; qt < 2; ++qt)
            #pragma unroll
            for (int kt2 = 0; kt2 < 2; ++kt2) {
                const float p0 = exp2f(st[kt2][qt][0]);
                const float p1 = exp2f(st[kt2][qt][1]);
                const float p2 = exp2f(st[kt2][qt][2]);
                const float p3 = exp2f(st[kt2][qt][3]);
                l_lane[qt] += (p0 + p1) + (p2 + p3);
                wq[qt][kt2][0] = cvtpk(p0, p1);
                wq[qt][kt2][1] = cvtpk(p2, p3);
            }

        // In-register P redistribution (round-2 verified pattern, tn->kt2).
        bf16x8 pf[2];
        #pragma unroll
        for (int qt = 0; qt < 2; ++qt) {
            unsigned int a0 = wq[qt][0][0], a2 = wq[qt][1][0];
            pl32(a0, a2); pl16(a0, a2);
            unsigned int a1 = wq[qt][0][1], a3 = wq[qt][1][1];
            pl32(a1, a3); pl16(a1, a3);
            const u32x4 u = {a0, a1, a2, a3};
            pf[qt] = __builtin_bit_cast(bf16x8, u);   // P[q=r16][k=quad*8+j]
        }

        // PV: o_acc[qt][dt] += P[16q x 32k-slice] * V[16d x 32k-slice]
        #pragma unroll
        for (int qt = 0; qt < 2; ++qt)
            #pragma unroll
            for (int dt = 0; dt < 4; ++dt)
                o_acc[qt][dt] = __builtin_amdgcn_mfma_f32_16x16x32_bf16(
                    pf[qt], vf[dt], o_acc[qt][dt], 0, 0, 0);
    }

    // l: quad-sum within wave -> lane r16 holds l over the wave's 32 k.
    float lq[2];
    #pragma unroll
    for (int qt = 0; qt < 2; ++qt) {
        float l = l_lane[qt];
        l += __shfl_xor(l, 16, 64);
        l += __shfl_xor(l, 32, 64);
        lq[qt] = l;
    }
    if (quad == 0) {
        lred[wave][r16]      = lq[0];
        lred[wave][16 + r16] = lq[1];
    }
    // ks=1 waves dump O partials. C layout: d = dt*16+r16, q_l = qt*16+quad*4+r.
    if (ks == 1) {
        #pragma unroll
        for (int qt = 0; qt < 2; ++qt)
            #pragma unroll
            for (int dt = 0; dt < 4; ++dt)
                #pragma unroll
                for (int r = 0; r < 4; ++r)
                    red[qh][(qt * 16 + quad * 4 + r) * 64 + dt * 16 + r16] = o_acc[qt][dt][r];
    }
    __syncthreads();
    if (ks == 0) {
        const int w2 = wave;   // = 2*qh
        #pragma unroll
        for (int qt = 0; qt < 2; ++qt) {
            float il[4];
            #pragma unroll
            for (int r = 0; r < 4; ++r) {
                const int ql = qt * 16 + quad * 4 + r;
                il[r] = 1.0f / (lred[w2][ql] + lred[w2 + 1][ql]);
            }
            #pragma unroll
            for (int dt = 0; dt < 4; ++dt)
                #pragma unroll
                for (int r = 0; r < 4; ++r) {
                    const int ql = qt * 16 + quad * 4 + r;
                    const float v = o_acc[qt][dt][r] + red[qh][ql * 64 + dt * 16 + r16];
                    O[base + (size_t)(qw0 + ql) * EE + dt * 16 + r16] = f2bf(v * il[r]);
                }
        }
    }
}

extern "C" void kernel_launch(void* const* d_in, const int* in_sizes, int n_in,
                              void* d_out, int out_size, void* d_ws, size_t ws_size,
                              hipStream_t stream) {
    const float* x   = (const float*)d_in[0];
    const float* ent = (const float*)d_in[1];
    const float* Wq  = (const float*)d_in[2];
    const float* bq  = (const float*)d_in[3];
    const float* Wk  = (const float*)d_in[4];
    const float* bk  = (const float*)d_in[5];
    const float* Wv  = (const float*)d_in[6];
    const float* bv  = (const float*)d_in[7];
    const float* Wo  = (const float*)d_in[8];
    const float* bo  = (const float*)d_in[9];
    float* out = (float*)d_out;

    const size_t n_x = (size_t)BB * SS * EE;   // 4 Mi elements
    const size_t n_w = (size_t)EE * EE;

    unsigned short* xb  = (unsigned short*)d_ws;
    unsigned short* wqb = xb + n_x;
    unsigned short* wkb = wqb + n_w;
    unsigned short* wvb = wkb + n_w;
    unsigned short* wob = wvb + n_w;
    unsigned short* Qb  = wob + n_w;
    unsigned short* Kb  = Qb + n_x;
    unsigned short* Vtb = Kb + n_x;   // [b][h][d][s]
    unsigned short* AOb = Vtb + n_x;

    const int M = BB * SS;  // 8192

    dim3 gc(4096, 5, 1);
    cast_all<<<gc, 256, 0, stream>>>(x, Wq, Wk, Wv, Wo, xb, wqb, wkb, wvb, wob);

    // Fused QKV projection; Q rows pre-scaled by ent*0.125*log2e.
    dim3 gq(M / 128, EE / 128, 3);
    gemm_mfma_nt<unsigned short, true, 128><<<gq, 256, 0, stream>>>(
        xb, wqb, bq, Qb, wkb, bk, Kb, wvb, bv, Vtb, ent, M, EE, EE);

    // Grid (h, qtile, b): head -> XCD for K/V L2 residency.
    dim3 ga(HH, SS / 64, BB);
    attn_mfma<<<ga, 256, 0, stream>>>(Qb, Kb, Vtb, AOb);

    // Out-proj: 64x128 tiles -> 512 blocks (2/CU).
    dim3 go(M / 64, EE / 128, 1);
    gemm_mfma_nt<float, false, 64><<<go, 256, 0, stream>>>(
        AOb, wob, bo, out, wob, bo, out, wob, bo, out, nullptr, M, EE, EE);
}

// Round 4
// 187.547 us; speedup vs baseline: 1.3244x; 1.3244x over previous
//
#include <hip/hip_runtime.h>
#include <hip/hip_bf16.h>

#define BB 4
#define SS 2048
#define EE 512
#define HH 8
#define DD 64

typedef __attribute__((ext_vector_type(8))) short bf16x8;   // 8 bf16 = 4 VGPRs
typedef __attribute__((ext_vector_type(4))) float f32x4;
typedef __attribute__((ext_vector_type(4))) unsigned int u32x4;

__device__ __forceinline__ unsigned short f2bf(float f) {
    __hip_bfloat16 h = __float2bfloat16(f);   // round-to-nearest
    return *reinterpret_cast<unsigned short*>(&h);
}

// HW packed f32->bf16 (RTNE). lo -> low 16, hi -> high 16 (T12 recipe).
__device__ __forceinline__ unsigned int cvtpk(float lo, float hi) {
    unsigned int r;
    asm("v_cvt_pk_bf16_f32 %0, %1, %2" : "=v"(r) : "v"(lo), "v"(hi));
    return r;
}

// gfx950 half-wave swaps (T12).
__device__ __forceinline__ void pl32(unsigned int& a, unsigned int& b) {
    asm("v_permlane32_swap_b32 %0, %1" : "+v"(a), "+v"(b));
}
__device__ __forceinline__ void pl16(unsigned int& a, unsigned int& b) {
    asm("v_permlane16_swap_b32 %0, %1" : "+v"(a), "+v"(b));
}

// Async global->LDS DMA, 16 B per lane. LDS dst = wave-uniform base + lane*16
// (m104/m108). Drained by the vmcnt(0) inside __syncthreads().
__device__ __forceinline__ void gll16(const unsigned short* g, unsigned short* l) {
    __builtin_amdgcn_global_load_lds(
        (const __attribute__((address_space(1))) unsigned int*)g,
        (__attribute__((address_space(3))) unsigned int*)l,
        16, 0, 0);
}

// ---------------------------------------------------------------------------
// fp32 -> bf16 cast, 5 tensors, exact-size 1D grid (no empty blocks).
// blocks [0,4096) -> x; then 256-block slices per weight.
// ---------------------------------------------------------------------------
__global__ __launch_bounds__(256)
void cast_all(const float* __restrict__ x,
              const float* __restrict__ wq, const float* __restrict__ wk,
              const float* __restrict__ wv, const float* __restrict__ wo,
              unsigned short* __restrict__ xb,
              unsigned short* __restrict__ wqb, unsigned short* __restrict__ wkb,
              unsigned short* __restrict__ wvb, unsigned short* __restrict__ wob)
{
    const int bid = blockIdx.x;
    const float* src; unsigned short* dst; int lb;
    if (bid < 4096)      { src = x;  dst = xb;  lb = bid; }
    else {
        const int t = (bid - 4096) >> 8;   // 0..3
        lb = (bid - 4096) & 255;
        switch (t) {
            case 0:  src = wq; dst = wqb; break;
            case 1:  src = wk; dst = wkb; break;
            case 2:  src = wv; dst = wvb; break;
            default: src = wo; dst = wob; break;
        }
    }
    const int i = lb * 256 + threadIdx.x;
    const float4 v = reinterpret_cast<const float4*>(src)[i];
    ushort4 o;
    o.x = f2bf(v.x); o.y = f2bf(v.y); o.z = f2bf(v.z); o.w = f2bf(v.w);
    reinterpret_cast<ushort4*>(dst)[i] = o;
}

// ---------------------------------------------------------------------------
// MFMA GEMM: C = A(bf16)[M,K] @ W(bf16)[N,K]^T + bias.
// TM x 128 tile, 4 waves, 16x16x32 bf16 MFMA, BK=32.
// Round 4: double-buffered stage-ahead DMA (attn round-2 pattern): stage(i+1)
// issued right after the single barrier, lands under compute(i); the
// vmcnt(0) inside the NEXT __syncthreads completes it. One barrier/K-step
// instead of two -> barrier-drain stall overlapped.
// TRANSPOSE_V: blockIdx.z==2 writes C transposed per-head as Vt[b][h][d][s].
// rowscale (non-null, z==0 only): (acc+bias) * rowscale[row&(SS-1)] *
// 0.125*log2e — folds attention's per-query entangle scale into Q.
// ---------------------------------------------------------------------------
template<typename OutT, bool TRANSPOSE_V, int TM>
__global__ __launch_bounds__(256)
void gemm_mfma_nt(const unsigned short* __restrict__ A,
                  const unsigned short* __restrict__ W0, const float* __restrict__ b0, OutT* __restrict__ C0,
                  const unsigned short* __restrict__ W1, const float* __restrict__ b1, OutT* __restrict__ C1,
                  const unsigned short* __restrict__ W2, const float* __restrict__ b2, OutT* __restrict__ C2,
                  const float* __restrict__ rowscale,
                  int M, int N, int K)
{
    const unsigned short* W = (blockIdx.z == 0) ? W0 : (blockIdx.z == 1) ? W1 : W2;
    const float* bias       = (blockIdx.z == 0) ? b0 : (blockIdx.z == 1) ? b1 : b2;
    OutT* C                 = (blockIdx.z == 0) ? C0 : (blockIdx.z == 1) ? C1 : C2;

    constexpr int MT = TM / 32;             // m-tiles of 16 per wave (4 or 2)
    __shared__ unsigned short As[2][TM * 32];   // [buf][row][32] chunk-swizzled
    __shared__ unsigned short Bs[2][128 * 32];

    const int tid  = threadIdx.x;
    const int wave = tid >> 6, lane = tid & 63;
    const int quad = lane >> 4, r16 = lane & 15;
    const int m0 = blockIdx.x * TM, n0 = blockIdx.y * 128;
    const int wm0 = (wave >> 1) * (TM / 2), wn0 = (wave & 1) * 64;

    f32x4 acc[MT][4];
    const f32x4 zero = {0.f, 0.f, 0.f, 0.f};
    #pragma unroll
    for (int i = 0; i < MT; ++i)
        #pragma unroll
        for (int j = 0; j < 4; ++j) acc[i][j] = zero;

    const int swz = (r16 >> 1) & 3;   // fragment-read chunk swizzle

    auto stage = [&](int bi, int k0) {
        #pragma unroll
        for (int j = 0; j < TM / 64; ++j) {
            const int cb = wave * 64 + j * 256;       // wave-uniform chunk base
            const int c  = cb + lane;                 // this lane's chunk
            const int row = c >> 2, cc = (c & 3) ^ ((row >> 1) & 3);
            gll16(&A[(size_t)(m0 + row) * K + k0 + cc * 8], &As[bi][cb * 8]);
        }
        #pragma unroll
        for (int j = 0; j < 2; ++j) {
            const int cb = wave * 64 + j * 256;
            const int c  = cb + lane;
            const int row = c >> 2, cc = (c & 3) ^ ((row >> 1) & 3);
            gll16(&W[(size_t)(n0 + row) * K + k0 + cc * 8], &Bs[bi][cb * 8]);
        }
    };

    stage(0, 0);

    const int NI = K / 32;
    for (int i = 0; i < NI; ++i) {
        const int cur = i & 1;
        __syncthreads();   // drains DMA for [cur]; prev frag reads all done
        if (i + 1 < NI) stage(cur ^ 1, (i + 1) * 32);   // lands under compute

        bf16x8 af[MT], bfr[4];
        #pragma unroll
        for (int t = 0; t < MT; ++t)
            af[t]  = *reinterpret_cast<bf16x8*>(&As[cur][((wm0 + t * 16 + r16) * 4 + (quad ^ swz)) * 8]);
        #pragma unroll
        for (int t = 0; t < 4; ++t)
            bfr[t] = *reinterpret_cast<bf16x8*>(&Bs[cur][((wn0 + t * 16 + r16) * 4 + (quad ^ swz)) * 8]);
        #pragma unroll
        for (int mt = 0; mt < MT; ++mt)
            #pragma unroll
            for (int nt = 0; nt < 4; ++nt)
                acc[mt][nt] = __builtin_amdgcn_mfma_f32_16x16x32_bf16(
                    af[mt], bfr[nt], acc[mt][nt], 0, 0, 0);
    }

    // Epilogue. C/D layout: col = lane&15, row = quad*4 + reg (m89-verified).
    if (TRANSPOSE_V && blockIdx.z == 2) {
        #pragma unroll
        for (int mt = 0; mt < MT; ++mt) {
            const int m = m0 + wm0 + mt * 16 + quad * 4;   // 4 consecutive rows
            const int bb = m >> 11, s0 = m & (SS - 1);
            #pragma unroll
            for (int nt = 0; nt < 4; ++nt) {
                const int col = n0 + wn0 + nt * 16 + r16;
                const float bv = bias[col];
                uint2 o;
                o.x = cvtpk(acc[mt][nt][0] + bv, acc[mt][nt][1] + bv);
                o.y = cvtpk(acc[mt][nt][2] + bv, acc[mt][nt][3] + bv);
                *reinterpret_cast<uint2*>(
                    &((unsigned short*)C2)[(size_t)bb * EE * SS + (size_t)col * SS + s0]) = o;
            }
        }
        return;
    }
    const bool doscale = (rowscale != nullptr) && (blockIdx.z == 0);
    #pragma unroll
    for (int mt = 0; mt < MT; ++mt) {
        float rs[4];
        #pragma unroll
        for (int r = 0; r < 4; ++r) {
            const int row = m0 + wm0 + mt * 16 + quad * 4 + r;
            rs[r] = doscale ? rowscale[row & (SS - 1)] * 0.18033688f : 1.0f;
        }
        #pragma unroll
        for (int nt = 0; nt < 4; ++nt) {
            const int col = n0 + wn0 + nt * 16 + r16;
            const float bv = bias[col];
            #pragma unroll
            for (int r = 0; r < 4; ++r) {
                const int row = m0 + wm0 + mt * 16 + quad * 4 + r;
                const float v = (acc[mt][nt][r] + bv) * rs[r];
                if constexpr (sizeof(OutT) == 2)
                    C[(size_t)row * N + col] = (OutT)f2bf(v);
                else
                    C[(size_t)row * N + col] = (OutT)v;
            }
        }
    }
}

// ---------------------------------------------------------------------------
// MFMA flash attention — round-2 version VERBATIM (76.7 us, verified).
// Round-3's staging removal regressed (latency-bound, VALUBusy 66->31):
// the double-buffered gll16 pipeline IS the latency-hiding engine.
//  - Q pre-scaled by entangle*0.125*log2e in the QKV GEMM.
//  - K/V DMA double-buffered, ONE barrier/iter.
//  - P in registers via cvt_pk + permlane32/16 swap (no Ps LDS).
//  - Grid (h, qtile, b): head -> XCD, K/V L2-resident (FETCH 12 MB).
// ---------------------------------------------------------------------------
__global__ __launch_bounds__(256)
void attn_mfma(const unsigned short* __restrict__ Q,
               const unsigned short* __restrict__ K,
               const unsigned short* __restrict__ Vt,
               unsigned short* __restrict__ O)
{
    __shared__ unsigned short Ks[2][64 * 64];    // [buf][k][64] chunk-swizzled
    __shared__ unsigned short Vs[2][64 * 64];    // [buf][d][64] chunk-swizzled

    const int tid  = threadIdx.x;
    const int wave = tid >> 6, lane = tid & 63;
    const int quad = lane >> 4, r16 = lane & 15;
    const int h  = blockIdx.x;                   // h on blockIdx.x -> XCD = h
    const int q0 = blockIdx.y * 64;
    const int b  = blockIdx.z;
    const size_t base    = (size_t)b * SS * EE + (size_t)h * DD;   // Q/K/O rows
    const size_t base_vt = ((size_t)b * HH + h) * DD * SS;         // Vt rows

    // Q fragments once, direct from global. B-operand: n = q = r16.
    const int qrow = q0 + wave * 16 + r16;
    bf16x8 qf0 = *reinterpret_cast<const bf16x8*>(&Q[base + (size_t)qrow * EE + quad * 8]);
    bf16x8 qf1 = *reinterpret_cast<const bf16x8*>(&Q[base + (size_t)qrow * EE + 32 + quad * 8]);

    // Staging lane geometry (loop-invariant).
    const int cb0 = wave * 64, cb1 = wave * 64 + 256;
    const int c0 = cb0 + lane, c1 = cb1 + lane;
    const int row0 = c0 >> 3, cc0 = (c0 & 7) ^ (row0 & 7);
    const int row1 = c1 >> 3, cc1 = (c1 & 7) ^ (row1 & 7);
    const unsigned short* kp0 = &K[base + (size_t)row0 * EE + cc0 * 8];
    const unsigned short* kp1 = &K[base + (size_t)row1 * EE + cc1 * 8];
    const unsigned short* vp0 = &Vt[base_vt + (size_t)row0 * SS + cc0 * 8];
    const unsigned short* vp1 = &Vt[base_vt + (size_t)row1 * SS + cc1 * 8];

    auto stage = [&](int bi, int kt) {
        const size_t ko = (size_t)kt * 64 * EE;   // K advances 64 rows/tile
        const int    vo = kt * 64;                // Vt advances 64 cols/tile
        gll16(kp0 + ko, &Ks[bi][cb0 * 8]);
        gll16(vp0 + vo, &Vs[bi][cb0 * 8]);
        gll16(kp1 + ko, &Ks[bi][cb1 * 8]);
        gll16(vp1 + vo, &Vs[bi][cb1 * 8]);
    };

    float l_lane = 0.f;
    f32x4 o_acc[4];
    const f32x4 zero = {0.f, 0.f, 0.f, 0.f};
    #pragma unroll
    for (int dt = 0; dt < 4; ++dt) o_acc[dt] = zero;

    const int swz = r16 & 7;   // fragment-read chunk swizzle (8 chunks/row)

    stage(0, 0);

    constexpr int NT = SS / 64;
    for (int kt = 0; kt < NT; ++kt) {
        const int cur = kt & 1;
        __syncthreads();   // drains DMA for [cur]; prev frag reads all done
        if (kt + 1 < NT) stage(cur ^ 1, kt + 1);   // lands under this compute

        // S^T = mfma(kf, qf): lane(quad,r16) gets st[tn][r] =
        //   S[q = r16][k = tn*16 + quad*4 + r].
        f32x4 st[4];
        #pragma unroll
        for (int tn = 0; tn < 4; ++tn) st[tn] = zero;
        #pragma unroll
        for (int tn = 0; tn < 4; ++tn) {
            bf16x8 kf0 = *reinterpret_cast<const bf16x8*>(&Ks[cur][((tn * 16 + r16) * 8 + (quad ^ swz)) * 8]);
            bf16x8 kf1 = *reinterpret_cast<const bf16x8*>(&Ks[cur][((tn * 16 + r16) * 8 + ((quad + 4) ^ swz)) * 8]);
            st[tn] = __builtin_amdgcn_mfma_f32_16x16x32_bf16(kf0, qf0, st[tn], 0, 0, 0);
            st[tn] = __builtin_amdgcn_mfma_f32_16x16x32_bf16(kf1, qf1, st[tn], 0, 0, 0);
        }

        // V fragments (independent of softmax -> overlaps it).
        bf16x8 vf0[4], vf1[4];
        #pragma unroll
        for (int dt = 0; dt < 4; ++dt) {
            vf0[dt] = *reinterpret_cast<const bf16x8*>(&Vs[cur][((dt * 16 + r16) * 8 + (quad ^ swz)) * 8]);
            vf1[dt] = *reinterpret_cast<const bf16x8*>(&Vs[cur][((dt * 16 + r16) * 8 + ((quad + 4) ^ swz)) * 8]);
        }

        // m=0 softmax (scale pre-folded into Q); pack to bf16 pairs in-reg.
        unsigned int w[4][2];
        #pragma unroll
        for (int tn = 0; tn < 4; ++tn) {
            const float p0 = exp2f(st[tn][0]);
            const float p1 = exp2f(st[tn][1]);
            const float p2 = exp2f(st[tn][2]);
            const float p3 = exp2f(st[tn][3]);
            l_lane += (p0 + p1) + (p2 + p3);
            w[tn][0] = cvtpk(p0, p1);
            w[tn][1] = cvtpk(p2, p3);
        }

        // In-register P redistribution (no LDS): for each hi, one pl32+pl16
        // on (w[tn], w[tn+1]) yields both A-operand words j=hi and j=hi+2.
        unsigned int pa0 = w[0][0], pa2 = w[1][0];
        pl32(pa0, pa2); pl16(pa0, pa2);
        unsigned int pa1 = w[0][1], pa3 = w[1][1];
        pl32(pa1, pa3); pl16(pa1, pa3);
        unsigned int pb0 = w[2][0], pb2 = w[3][0];
        pl32(pb0, pb2); pl16(pb0, pb2);
        unsigned int pb1 = w[2][1], pb3 = w[3][1];
        pl32(pb1, pb3); pl16(pb1, pb3);

        const u32x4 ua = {pa0, pa1, pa2, pa3};
        const u32x4 ub = {pb0, pb1, pb2, pb3};
        const bf16x8 pf0 = __builtin_bit_cast(bf16x8, ua);  // P[q=r16][quad*8+j]
        const bf16x8 pf1 = __builtin_bit_cast(bf16x8, ub);  // P[q=r16][32+quad*8+j]

        // PV: a = P[m=q=r16][k = quad*8+j], b = Vs[n=d=r16][k].
        #pragma unroll
        for (int dt = 0; dt < 4; ++dt) {
            o_acc[dt] = __builtin_amdgcn_mfma_f32_16x16x32_bf16(pf0, vf0[dt], o_acc[dt], 0, 0, 0);
            o_acc[dt] = __builtin_amdgcn_mfma_f32_16x16x32_bf16(pf1, vf1[dt], o_acc[dt], 0, 0, 0);
        }
    }

    // l: per-lane total for q = r16; sum the 4 quads.
    float l = l_lane;
    l += __shfl_xor(l, 16, 64);
    l += __shfl_xor(l, 32, 64);

    // Epilogue: O rows q = quad*4+r; l for that q lives in lane (quad*4+r).
    #pragma unroll
    for (int r = 0; r < 4; ++r) {
        const float il = 1.0f / __shfl(l, quad * 4 + r, 64);
        const int q = q0 + wave * 16 + quad * 4 + r;
        #pragma unroll
        for (int dt = 0; dt < 4; ++dt)
            O[base + (size_t)q * EE + dt * 16 + r16] = f2bf(o_acc[dt][r] * il);
    }
}

extern "C" void kernel_launch(void* const* d_in, const int* in_sizes, int n_in,
                              void* d_out, int out_size, void* d_ws, size_t ws_size,
                              hipStream_t stream) {
    const float* x   = (const float*)d_in[0];
    const float* ent = (const float*)d_in[1];
    const float* Wq  = (const float*)d_in[2];
    const float* bq  = (const float*)d_in[3];
    const float* Wk  = (const float*)d_in[4];
    const float* bk  = (const float*)d_in[5];
    const float* Wv  = (const float*)d_in[6];
    const float* bv  = (const float*)d_in[7];
    const float* Wo  = (const float*)d_in[8];
    const float* bo  = (const float*)d_in[9];
    float* out = (float*)d_out;

    const size_t n_x = (size_t)BB * SS * EE;   // 4 Mi elements
    const size_t n_w = (size_t)EE * EE;

    unsigned short* xb  = (unsigned short*)d_ws;
    unsigned short* wqb = xb + n_x;
    unsigned short* wkb = wqb + n_w;
    unsigned short* wvb = wkb + n_w;
    unsigned short* wob = wvb + n_w;
    unsigned short* Qb  = wob + n_w;
    unsigned short* Kb  = Qb + n_x;
    unsigned short* Vtb = Kb + n_x;   // [b][h][d][s]
    unsigned short* AOb = Vtb + n_x;

    const int M = BB * SS;  // 8192

    // Exact-size cast grid: 4096 (x) + 4*256 (weights).
    dim3 gc(4096 + 4 * 256, 1, 1);
    cast_all<<<gc, 256, 0, stream>>>(x, Wq, Wk, Wv, Wo, xb, wqb, wkb, wvb, wob);

    // Fused QKV projection; Q rows pre-scaled by ent*0.125*log2e.
    dim3 gq(M / 128, EE / 128, 3);
    gemm_mfma_nt<unsigned short, true, 128><<<gq, 256, 0, stream>>>(
        xb, wqb, bq, Qb, wkb, bk, Kb, wvb, bv, Vtb, ent, M, EE, EE);

    // Grid (h, qtile, b): head -> XCD for K/V L2 residency.
    dim3 ga(HH, SS / 64, BB);
    attn_mfma<<<ga, 256, 0, stream>>>(Qb, Kb, Vtb, AOb);

    // Out-proj: 64x128 tiles -> 512 blocks (2/CU).
    dim3 go(M / 64, EE / 128, 1);
    gemm_mfma_nt<float, false, 64><<<go, 256, 0, stream>>>(
        AOb, wob, bo, out, wob, bo, out, wob, bo, out, nullptr, M, EE, EE);
}